// Round 1
// baseline (457.879 us; speedup 1.0000x reference)
//
#include <hip/hip_runtime.h>

// ---------------------------------------------------------------------------
// KernelClassifier: px = x@Wp+bp; pX = X@Wp+bp; Kis = exp(-||px-pX||^2/256)
// (drop self: Kis<1.0f), pred[b,lab[i]] += Kis[b,i], normalize, rank-gather.
// lab[i] = descending rank of SorP_train[i, Y[i]]; output reordered by ranks
// of SorP_q rows.
// ---------------------------------------------------------------------------

typedef short  bf8v  __attribute__((ext_vector_type(8)));   // 8 x bf16 (4 VGPR)
typedef float  f32x4 __attribute__((ext_vector_type(4)));   // MFMA C/D

#define NTRAIN 50000
#define NPAD   50048          // 391 * 128
#define NTILES 391
#define NCHUNK 64
#define BQ     1024
#define DIN    768
#define DP     128
#define NCLS   100
#define PSTRIDE 130           // LDS pred row stride (floats): bank = (2b+c)%32

__device__ __forceinline__ short f2bf(float x) {   // fp32 -> bf16 RNE
    unsigned u = __float_as_uint(x);
    u += 0x7FFFu + ((u >> 16) & 1u);
    return (short)(u >> 16);
}

// ---------------------------------------------------------------------------
// Kernel 0: pack Wp into B-fragment order: WpP[q][cb][lane][j] =
//   bf16(Wp[32q + 8*(lane>>4) + j][16cb + (lane&15)])
// ---------------------------------------------------------------------------
__global__ __launch_bounds__(256) void k_pack_wp(const float* __restrict__ Wp,
                                                 short* __restrict__ WpP) {
    int tid = blockIdx.x * 256 + threadIdx.x;
    if (tid >= 24 * 8 * 64) return;
    int l = tid & 63, cb = (tid >> 6) & 7, q = tid >> 9;
    int c = cb * 16 + (l & 15);
    int g = l >> 4;
    bf8v o;
#pragma unroll
    for (int j = 0; j < 8; ++j) {
        int k = q * 32 + g * 8 + j;
        o[j] = f2bf(Wp[k * DP + c]);
    }
    *reinterpret_cast<bf8v*>(WpP + (size_t)tid * 8) = o;
}

// ---------------------------------------------------------------------------
// Kernel 1: projection GEMM  out = rows @ Wp + bp   (K=768, Ncols=128)
// BM=128 rows/block, 4 waves, each wave 32 rows x 128 cols.
// Writes: fragment-packed bf16 rows (A-frag and B-frag packing formulas are
// identical) + squared norms (pad rows: norm=1e30, values=0).
// ---------------------------------------------------------------------------
__global__ __launch_bounds__(256) void k_proj(const float* __restrict__ Xin,
                                              const short* __restrict__ WpP,
                                              const float* __restrict__ bp,
                                              short* __restrict__ outP,
                                              float* __restrict__ normv,
                                              int Mreal) {
    __shared__ __align__(16) short Alds[128 * 64];   // bf16 tile, XOR-swizzled
    const int tid = threadIdx.x;
    const int w = tid >> 6, l = tid & 63, g = l >> 4, li = l & 15;
    const int rowblk = blockIdx.x * 128;

    f32x4 acc[2][8];
#pragma unroll
    for (int rb = 0; rb < 2; ++rb)
#pragma unroll
        for (int cb = 0; cb < 8; ++cb) acc[rb][cb] = (f32x4){0.f, 0.f, 0.f, 0.f};

    for (int kb = 0; kb < 12; ++kb) {          // K-step = 64
        __syncthreads();                        // protect previous reads
#pragma unroll
        for (int it = 0; it < 8; ++it) {        // stage A: 128x64 fp32 -> bf16
            int s = tid + 256 * it;             // 0..2047
            int row = s >> 4, k4 = (s & 15) * 4;
            float4 v = make_float4(0.f, 0.f, 0.f, 0.f);
            if (rowblk + row < Mreal)
                v = *reinterpret_cast<const float4*>(
                        Xin + (size_t)(rowblk + row) * DIN + kb * 64 + k4);
            unsigned lo = (unsigned short)f2bf(v.x) |
                          ((unsigned)(unsigned short)f2bf(v.y) << 16);
            unsigned hi = (unsigned short)f2bf(v.z) |
                          ((unsigned)(unsigned short)f2bf(v.w) << 16);
            int byte = (row * 128 + k4 * 2) ^ ((row & 7) << 4);
            *reinterpret_cast<uint2*>((char*)Alds + byte) = make_uint2(lo, hi);
        }
        __syncthreads();
#pragma unroll
        for (int kc = 0; kc < 2; ++kc) {
            const int q = kb * 2 + kc;
            bf8v a[2];
#pragma unroll
            for (int rb = 0; rb < 2; ++rb) {
                int row = w * 32 + rb * 16 + li;
                int byte = (row * 128 + kc * 64 + g * 16) ^ ((row & 7) << 4);
                a[rb] = *reinterpret_cast<const bf8v*>((const char*)Alds + byte);
            }
#pragma unroll
            for (int cb = 0; cb < 8; ++cb) {
                bf8v b = *reinterpret_cast<const bf8v*>(
                             WpP + (size_t)((q * 8 + cb) * 64 + l) * 8);
                acc[0][cb] = __builtin_amdgcn_mfma_f32_16x16x32_bf16(
                                 a[0], b, acc[0][cb], 0, 0, 0);
                acc[1][cb] = __builtin_amdgcn_mfma_f32_16x16x32_bf16(
                                 a[1], b, acc[1][cb], 0, 0, 0);
            }
        }
    }

    // epilogue: bias, norms (reduce across the 16 lanes sharing a row), pack
    float bpv[8];
#pragma unroll
    for (int cb = 0; cb < 8; ++cb) bpv[cb] = bp[cb * 16 + li];
#pragma unroll
    for (int rb = 0; rb < 2; ++rb)
#pragma unroll
        for (int cb = 0; cb < 8; ++cb)
#pragma unroll
            for (int r = 0; r < 4; ++r) acc[rb][cb][r] += bpv[cb];

#pragma unroll
    for (int rb = 0; rb < 2; ++rb)
#pragma unroll
        for (int r = 0; r < 4; ++r) {
            float s = 0.f;
#pragma unroll
            for (int cb = 0; cb < 8; ++cb) {
                float v = acc[rb][cb][r];
                s += v * v;
            }
            s += __shfl_xor(s, 1);
            s += __shfl_xor(s, 2);
            s += __shfl_xor(s, 4);
            s += __shfl_xor(s, 8);
            int grow = rowblk + w * 32 + rb * 16 + 4 * g + r;
            if (li == 0) normv[grow] = (grow < Mreal) ? s : 1e30f;
        }

#pragma unroll
    for (int rb = 0; rb < 2; ++rb)
#pragma unroll
        for (int cb = 0; cb < 8; ++cb) {
            int d = cb * 16 + li;
            int q = d >> 5, g2 = (d & 31) >> 3, j = d & 7;
#pragma unroll
            for (int r = 0; r < 4; ++r) {
                int grow = rowblk + w * 32 + rb * 16 + 4 * g + r;
                float v = (grow < Mreal) ? acc[rb][cb][r] : 0.f;
                size_t e = ((size_t)((grow >> 4) * 4 + q) * 64 +
                            (g2 * 16 + (grow & 15))) * 8 + j;
                outP[e] = f2bf(v);
            }
        }
}

// ---------------------------------------------------------------------------
// Kernel 2: lab[i] = rank of SorP_train[i, Y[i]] in stable descending argsort
// = #{c: v_c > t} + #{c < y: v_c == t}.  One wave per row.
// ---------------------------------------------------------------------------
__global__ __launch_bounds__(256) void k_labels(const float* __restrict__ S,
                                                const int* __restrict__ Y,
                                                int* __restrict__ lab) {
    int w = threadIdx.x >> 6, l = threadIdx.x & 63;
    int i = blockIdx.x * 4 + w;
    if (i >= NPAD) return;
    int cnt = 0;
    if (i < NTRAIN) {
        int y = Y[i];
        float t = S[(size_t)i * NCLS + y];
        float v1 = S[(size_t)i * NCLS + l];                 // c = l < 100
        bool p1 = (v1 > t) || (v1 == t && l < y);
        unsigned long long b1 = __ballot(p1);
        bool p2 = false;
        if (l < NCLS - 64) {                                // c = 64 + l
            float v2 = S[(size_t)i * NCLS + 64 + l];
            p2 = (v2 > t) || (v2 == t && (64 + l) < y);
        }
        unsigned long long b2 = __ballot(p2);
        cnt = __popcll(b1) + __popcll(b2);
    }
    if (l == 0) lab[i] = cnt;
}

// ---------------------------------------------------------------------------
// Kernel 3: zero the pred accumulator
// ---------------------------------------------------------------------------
__global__ __launch_bounds__(256) void k_zero(float* __restrict__ p, int n) {
    int i = blockIdx.x * 256 + threadIdx.x;
    if (i < n) p[i] = 0.f;
}

// ---------------------------------------------------------------------------
// Kernel 4: main fused kernel.
// Grid (8 b-tiles, 64 chunks), 256 thr. Per block: 128 q-rows; wave w owns
// rows [32w,32w+32). Per i-tile (128): S = px @ pX^T via MFMA (B-frags direct
// from packed global), Kis = exp(-(qn+kn-2dot)/256), drop-self (Kis<1.0f),
// ds_add_f32 into per-wave LDS bins by lab[i]; epilogue atomicAdd to pred.
// ---------------------------------------------------------------------------
__global__ __launch_bounds__(256) void k_main(const short* __restrict__ pxp,
                                              const short* __restrict__ pXp,
                                              const float* __restrict__ qn,
                                              const float* __restrict__ kn,
                                              const int* __restrict__ lab,
                                              float* __restrict__ pred) {
    __shared__ __align__(16) float plds[128 * PSTRIDE];
    const int tid = threadIdx.x;
    const int w = tid >> 6, l = tid & 63, g = l >> 4, li = l & 15;
    const int bt = blockIdx.x;       // 0..7
    const int ch = blockIdx.y;       // 0..63

    for (int s = tid; s < 128 * PSTRIDE; s += 256) plds[s] = 0.f;
    __syncthreads();                 // only barrier in the kernel

    bf8v af[2][4];                   // px A-frags, persistent
#pragma unroll
    for (int rb = 0; rb < 2; ++rb)
#pragma unroll
        for (int q = 0; q < 4; ++q) {
            int RB = bt * 8 + w * 2 + rb;
            af[rb][q] = *reinterpret_cast<const bf8v*>(
                            pxp + (size_t)((RB * 4 + q) * 64 + l) * 8);
        }
    float qnv[2][4];
#pragma unroll
    for (int rb = 0; rb < 2; ++rb)
#pragma unroll
        for (int r = 0; r < 4; ++r)
            qnv[rb][r] = qn[bt * 128 + w * 32 + rb * 16 + 4 * g + r];

#pragma unroll 1
    for (int t = ch; t < NTILES; t += NCHUNK) {
        const int i0 = t * 128;
        for (int ib = 0; ib < 8; ++ib) {
            const int RBi = (i0 >> 4) + ib;
            bf8v bfr[4];
#pragma unroll
            for (int q = 0; q < 4; ++q)
                bfr[q] = *reinterpret_cast<const bf8v*>(
                             pXp + (size_t)((RBi * 4 + q) * 64 + l) * 8);
            f32x4 s0 = (f32x4){0.f, 0.f, 0.f, 0.f};
            f32x4 s1 = (f32x4){0.f, 0.f, 0.f, 0.f};
#pragma unroll
            for (int q = 0; q < 4; ++q) {
                s0 = __builtin_amdgcn_mfma_f32_16x16x32_bf16(af[0][q], bfr[q], s0, 0, 0, 0);
                s1 = __builtin_amdgcn_mfma_f32_16x16x32_bf16(af[1][q], bfr[q], s1, 0, 0, 0);
            }
            const int ii = i0 + ib * 16 + li;    // this lane's train index
            const float knv = kn[ii];
            const int   labv = lab[ii];
#pragma unroll
            for (int rb = 0; rb < 2; ++rb) {
                f32x4 sv = rb ? s1 : s0;
#pragma unroll
                for (int r = 0; r < 4; ++r) {
                    float sqd = qnv[rb][r] + knv - 2.f * sv[r];
                    float kis = __expf(sqd * (-1.f / 256.f));
                    kis = (kis < 1.0f) ? kis : 0.f;   // drop_self (1-1e-10 == 1.0f)
                    int rowl = w * 32 + rb * 16 + 4 * g + r;
                    atomicAdd(&plds[rowl * PSTRIDE + labv], kis);
                }
            }
        }
    }

    // epilogue: each wave flushes its own rows (same-wave LDS ordering)
#pragma unroll 1
    for (int rr = 0; rr < 32; ++rr) {
        int row = w * 32 + rr;
        float2 v = *reinterpret_cast<const float2*>(&plds[row * PSTRIDE + l * 2]);
        int grow = bt * 128 + row;
        atomicAdd(&pred[(size_t)grow * 128 + l * 2],     v.x);
        atomicAdd(&pred[(size_t)grow * 128 + l * 2 + 1], v.y);
    }
}

// ---------------------------------------------------------------------------
// Kernel 5: normalize + rank-gather.  out[b,c] = pred[b, rank_q(b,c)] / sum.
// ---------------------------------------------------------------------------
__global__ __launch_bounds__(128) void k_final(const float* __restrict__ pred,
                                               const float* __restrict__ SorPq,
                                               float* __restrict__ out) {
    __shared__ float sp[NCLS];
    __shared__ float pr[128];
    int b = blockIdx.x, c = threadIdx.x;
    if (c < NCLS) sp[c] = SorPq[(size_t)b * NCLS + c];
    pr[c] = pred[(size_t)b * 128 + c];
    __syncthreads();
    float tot = 0.f;
    for (int k = 0; k < NCLS; ++k) tot += pr[k];   // broadcast reads, deterministic
    if (c < NCLS) {
        float s = sp[c];
        int r = 0;
        for (int k = 0; k < NCLS; ++k) {
            float sk = sp[k];
            r += (sk > s || (sk == s && k < c)) ? 1 : 0;
        }
        out[(size_t)b * NCLS + c] = pr[r] / tot;
    }
}

// ---------------------------------------------------------------------------
extern "C" void kernel_launch(void* const* d_in, const int* in_sizes, int n_in,
                              void* d_out, int out_size, void* d_ws, size_t ws_size,
                              hipStream_t stream) {
    const float* x    = (const float*)d_in[0];   // [1024,768]
    const float* X    = (const float*)d_in[1];   // [50000,768]
    const float* Wp   = (const float*)d_in[2];   // [768,128]
    const float* bp   = (const float*)d_in[3];   // [128]
    const int*   Y    = (const int*)  d_in[4];   // [50000]
    const float* SPt  = (const float*)d_in[5];   // [50000,100]
    const float* SPq  = (const float*)d_in[6];   // [1024,100]
    float* out = (float*)d_out;                  // [1024,100]

    char* ws = (char*)d_ws;
    // ws layout (bytes), all 16B-aligned
    short* WpP = (short*)(ws + 0);                       //   196,608
    short* pXp = (short*)(ws + 196608);                  // 12,812,288
    short* pxq = (short*)(ws + 13008896);                //    262,144
    float* kn  = (float*)(ws + 13271040);                //    200,192
    float* qn  = (float*)(ws + 13471232);                //      4,096
    int*   lab = (int*)  (ws + 13475328);                //    200,192
    float* pred= (float*)(ws + 13675520);                //    524,288  (end 14,199,808)

    k_pack_wp<<<48, 256, 0, stream>>>(Wp, WpP);
    k_proj<<<NPAD / 128, 256, 0, stream>>>(X, WpP, bp, pXp, kn, NTRAIN);
    k_proj<<<BQ / 128,   256, 0, stream>>>(x, WpP, bp, pxq, qn, BQ);
    k_labels<<<NPAD / 4, 256, 0, stream>>>(SPt, Y, lab);
    k_zero<<<(BQ * 128) / 256, 256, 0, stream>>>(pred, BQ * 128);
    k_main<<<dim3(8, NCHUNK), 256, 0, stream>>>(pxq, pXp, qn, kn, lab, pred);
    k_final<<<BQ, 128, 0, stream>>>(pred, SPq, out);
}

// Round 3
// 451.049 us; speedup vs baseline: 1.0151x; 1.0151x over previous
//
#include <hip/hip_runtime.h>

// ---------------------------------------------------------------------------
// KernelClassifier: px = x@Wp+bp; pX = X@Wp+bp; Kis = exp(-||px-pX||^2/256)
// (drop self: Kis<1.0f), pred[b,lab[i]] += Kis[b,i], normalize, rank-gather.
// R2: global-atomic epilogue (64MB RMW, 322us) -> per-chunk partials + fused
// reduction; LDS 66.5->53.2KB (3 blk/CU); NCH 96; ch-major grid for XCD reuse.
// R3: fix k_final launch arity (compile error in R2).
// ---------------------------------------------------------------------------

typedef short  bf8v  __attribute__((ext_vector_type(8)));   // 8 x bf16 (4 VGPR)
typedef float  f32x4 __attribute__((ext_vector_type(4)));   // MFMA C/D

#define NTRAIN 50000
#define NPAD   50048          // 391 * 128
#define NTILES 391
#define BQ     1024
#define DIN    768
#define DP     128
#define NCLS   100
#define PSTRIDE 104           // LDS pred row stride (floats); 128*104*4=53248B
#define PCOLS  104            // partial row width (>=100, float2-aligned)

__device__ __forceinline__ short f2bf(float x) {   // fp32 -> bf16 RNE
    unsigned u = __float_as_uint(x);
    u += 0x7FFFu + ((u >> 16) & 1u);
    return (short)(u >> 16);
}

// ---------------------------------------------------------------------------
// Kernel 0: pack Wp into B-fragment order
// ---------------------------------------------------------------------------
__global__ __launch_bounds__(256) void k_pack_wp(const float* __restrict__ Wp,
                                                 short* __restrict__ WpP) {
    int tid = blockIdx.x * 256 + threadIdx.x;
    if (tid >= 24 * 8 * 64) return;
    int l = tid & 63, cb = (tid >> 6) & 7, q = tid >> 9;
    int c = cb * 16 + (l & 15);
    int g = l >> 4;
    bf8v o;
#pragma unroll
    for (int j = 0; j < 8; ++j) {
        int k = q * 32 + g * 8 + j;
        o[j] = f2bf(Wp[k * DP + c]);
    }
    *reinterpret_cast<bf8v*>(WpP + (size_t)tid * 8) = o;
}

// ---------------------------------------------------------------------------
// Kernel 1: projection GEMM  out = rows @ Wp + bp   (K=768, Ncols=128)
// ---------------------------------------------------------------------------
__global__ __launch_bounds__(256) void k_proj(const float* __restrict__ Xin,
                                              const short* __restrict__ WpP,
                                              const float* __restrict__ bp,
                                              short* __restrict__ outP,
                                              float* __restrict__ normv,
                                              int Mreal) {
    __shared__ __align__(16) short Alds[128 * 64];   // bf16 tile, XOR-swizzled
    const int tid = threadIdx.x;
    const int w = tid >> 6, l = tid & 63, g = l >> 4, li = l & 15;
    const int rowblk = blockIdx.x * 128;

    f32x4 acc[2][8];
#pragma unroll
    for (int rb = 0; rb < 2; ++rb)
#pragma unroll
        for (int cb = 0; cb < 8; ++cb) acc[rb][cb] = (f32x4){0.f, 0.f, 0.f, 0.f};

    for (int kb = 0; kb < 12; ++kb) {          // K-step = 64
        __syncthreads();                        // protect previous reads
#pragma unroll
        for (int it = 0; it < 8; ++it) {        // stage A: 128x64 fp32 -> bf16
            int s = tid + 256 * it;             // 0..2047
            int row = s >> 4, k4 = (s & 15) * 4;
            float4 v = make_float4(0.f, 0.f, 0.f, 0.f);
            if (rowblk + row < Mreal)
                v = *reinterpret_cast<const float4*>(
                        Xin + (size_t)(rowblk + row) * DIN + kb * 64 + k4);
            unsigned lo = (unsigned short)f2bf(v.x) |
                          ((unsigned)(unsigned short)f2bf(v.y) << 16);
            unsigned hi = (unsigned short)f2bf(v.z) |
                          ((unsigned)(unsigned short)f2bf(v.w) << 16);
            int byte = (row * 128 + k4 * 2) ^ ((row & 7) << 4);
            *reinterpret_cast<uint2*>((char*)Alds + byte) = make_uint2(lo, hi);
        }
        __syncthreads();
#pragma unroll
        for (int kc = 0; kc < 2; ++kc) {
            const int q = kb * 2 + kc;
            bf8v a[2];
#pragma unroll
            for (int rb = 0; rb < 2; ++rb) {
                int row = w * 32 + rb * 16 + li;
                int byte = (row * 128 + kc * 64 + g * 16) ^ ((row & 7) << 4);
                a[rb] = *reinterpret_cast<const bf8v*>((const char*)Alds + byte);
            }
#pragma unroll
            for (int cb = 0; cb < 8; ++cb) {
                bf8v b = *reinterpret_cast<const bf8v*>(
                             WpP + (size_t)((q * 8 + cb) * 64 + l) * 8);
                acc[0][cb] = __builtin_amdgcn_mfma_f32_16x16x32_bf16(
                                 a[0], b, acc[0][cb], 0, 0, 0);
                acc[1][cb] = __builtin_amdgcn_mfma_f32_16x16x32_bf16(
                                 a[1], b, acc[1][cb], 0, 0, 0);
            }
        }
    }

    // epilogue: bias, norms, pack
    float bpv[8];
#pragma unroll
    for (int cb = 0; cb < 8; ++cb) bpv[cb] = bp[cb * 16 + li];
#pragma unroll
    for (int rb = 0; rb < 2; ++rb)
#pragma unroll
        for (int cb = 0; cb < 8; ++cb)
#pragma unroll
            for (int r = 0; r < 4; ++r) acc[rb][cb][r] += bpv[cb];

#pragma unroll
    for (int rb = 0; rb < 2; ++rb)
#pragma unroll
        for (int r = 0; r < 4; ++r) {
            float s = 0.f;
#pragma unroll
            for (int cb = 0; cb < 8; ++cb) {
                float v = acc[rb][cb][r];
                s += v * v;
            }
            s += __shfl_xor(s, 1);
            s += __shfl_xor(s, 2);
            s += __shfl_xor(s, 4);
            s += __shfl_xor(s, 8);
            int grow = rowblk + w * 32 + rb * 16 + 4 * g + r;
            if (li == 0) normv[grow] = (grow < Mreal) ? s : 1e30f;
        }

#pragma unroll
    for (int rb = 0; rb < 2; ++rb)
#pragma unroll
        for (int cb = 0; cb < 8; ++cb) {
            int d = cb * 16 + li;
            int q = d >> 5, g2 = (d & 31) >> 3, j = d & 7;
#pragma unroll
            for (int r = 0; r < 4; ++r) {
                int grow = rowblk + w * 32 + rb * 16 + 4 * g + r;
                float v = (grow < Mreal) ? acc[rb][cb][r] : 0.f;
                size_t e = ((size_t)((grow >> 4) * 4 + q) * 64 +
                            (g2 * 16 + (grow & 15))) * 8 + j;
                outP[e] = f2bf(v);
            }
        }
}

// ---------------------------------------------------------------------------
// Kernel 2: lab[i] = stable descending rank of SorP_train[i, Y[i]]
// ---------------------------------------------------------------------------
__global__ __launch_bounds__(256) void k_labels(const float* __restrict__ S,
                                                const int* __restrict__ Y,
                                                int* __restrict__ lab) {
    int w = threadIdx.x >> 6, l = threadIdx.x & 63;
    int i = blockIdx.x * 4 + w;
    if (i >= NPAD) return;
    int cnt = 0;
    if (i < NTRAIN) {
        int y = Y[i];
        float t = S[(size_t)i * NCLS + y];
        float v1 = S[(size_t)i * NCLS + l];
        bool p1 = (v1 > t) || (v1 == t && l < y);
        unsigned long long b1 = __ballot(p1);
        bool p2 = false;
        if (l < NCLS - 64) {
            float v2 = S[(size_t)i * NCLS + 64 + l];
            p2 = (v2 > t) || (v2 == t && (64 + l) < y);
        }
        unsigned long long b2 = __ballot(p2);
        cnt = __popcll(b1) + __popcll(b2);
    }
    if (l == 0) lab[i] = cnt;
}

// ---------------------------------------------------------------------------
// Kernel 4: main fused kernel. Grid (NCH, 8): ch = blockIdx.x (XCD = ch%8 so
// the 8 b-tiles sharing pX tiles co-locate per XCD), bt = blockIdx.y.
// Per i-tile: S = px @ pX^T via MFMA, Kis = exp(-(qn+kn-2dot)/256), drop-self,
// ds_add_f32 LDS bins by lab[i]; epilogue: plain stores to per-chunk partial.
// ---------------------------------------------------------------------------
__global__ __launch_bounds__(256) void k_main(const short* __restrict__ pxp,
                                              const short* __restrict__ pXp,
                                              const float* __restrict__ qn,
                                              const float* __restrict__ kn,
                                              const int* __restrict__ lab,
                                              float* __restrict__ part,
                                              int NCH) {
    __shared__ __align__(16) float plds[128 * PSTRIDE];
    const int tid = threadIdx.x;
    const int w = tid >> 6, l = tid & 63, g = l >> 4, li = l & 15;
    const int ch = blockIdx.x;
    const int bt = blockIdx.y;       // 0..7

    for (int s = tid; s < 128 * PSTRIDE; s += 256) plds[s] = 0.f;
    __syncthreads();                 // only barrier in the kernel

    bf8v af[2][4];                   // px A-frags, persistent
#pragma unroll
    for (int rb = 0; rb < 2; ++rb)
#pragma unroll
        for (int q = 0; q < 4; ++q) {
            int RB = bt * 8 + w * 2 + rb;
            af[rb][q] = *reinterpret_cast<const bf8v*>(
                            pxp + (size_t)((RB * 4 + q) * 64 + l) * 8);
        }
    float qnv[2][4];
#pragma unroll
    for (int rb = 0; rb < 2; ++rb)
#pragma unroll
        for (int r = 0; r < 4; ++r)
            qnv[rb][r] = qn[bt * 128 + w * 32 + rb * 16 + 4 * g + r];

#pragma unroll 1
    for (int t = ch; t < NTILES; t += NCH) {
        const int i0 = t * 128;
        for (int ib = 0; ib < 8; ++ib) {
            const int RBi = (i0 >> 4) + ib;
            bf8v bfr[4];
#pragma unroll
            for (int q = 0; q < 4; ++q)
                bfr[q] = *reinterpret_cast<const bf8v*>(
                             pXp + (size_t)((RBi * 4 + q) * 64 + l) * 8);
            f32x4 s0 = (f32x4){0.f, 0.f, 0.f, 0.f};
            f32x4 s1 = (f32x4){0.f, 0.f, 0.f, 0.f};
#pragma unroll
            for (int q = 0; q < 4; ++q) {
                s0 = __builtin_amdgcn_mfma_f32_16x16x32_bf16(af[0][q], bfr[q], s0, 0, 0, 0);
                s1 = __builtin_amdgcn_mfma_f32_16x16x32_bf16(af[1][q], bfr[q], s1, 0, 0, 0);
            }
            const int ii = i0 + ib * 16 + li;    // this lane's train index
            const float knv = kn[ii];
            const int   labv = lab[ii];
#pragma unroll
            for (int rb = 0; rb < 2; ++rb) {
                f32x4 sv = rb ? s1 : s0;
#pragma unroll
                for (int r = 0; r < 4; ++r) {
                    float sqd = qnv[rb][r] + knv - 2.f * sv[r];
                    float kis = __expf(sqd * (-1.f / 256.f));
                    kis = (kis < 1.0f) ? kis : 0.f;   // drop_self (1-1e-10 == 1.0f)
                    int rowl = w * 32 + rb * 16 + 4 * g + r;
                    atomicAdd(&plds[rowl * PSTRIDE + labv], kis);
                }
            }
        }
    }

    // epilogue: each wave flushes its own rows with plain vectorized stores
#pragma unroll 1
    for (int rr = 0; rr < 32; ++rr) {
        int row = w * 32 + rr;
        if (l < PCOLS / 2) {
            float2 v = *reinterpret_cast<const float2*>(&plds[row * PSTRIDE + l * 2]);
            int grow = bt * 128 + row;
            *reinterpret_cast<float2*>(
                &part[((size_t)grow * NCH + ch) * PCOLS + l * 2]) = v;
        }
    }
}

// ---------------------------------------------------------------------------
// Kernel 5: fused reduce + normalize + rank-gather.
// Block b: pr[c] = sum_ch part[b][ch][c]; out[b,c] = pr[rank_q(b,c)] / sum.
// ---------------------------------------------------------------------------
__global__ __launch_bounds__(128) void k_final(const float* __restrict__ part,
                                               const float* __restrict__ SorPq,
                                               float* __restrict__ out,
                                               int NCH) {
    __shared__ float sp[NCLS];
    __shared__ float pr[PCOLS];
    int b = blockIdx.x, c = threadIdx.x;
    if (c < NCLS) sp[c] = SorPq[(size_t)b * NCLS + c];
    if (c < PCOLS) {
        float s = 0.f;
        const float* p = part + (size_t)b * NCH * PCOLS + c;
        for (int ch = 0; ch < NCH; ++ch) s += p[(size_t)ch * PCOLS];
        pr[c] = s;
    }
    __syncthreads();
    float tot = 0.f;
    for (int k = 0; k < NCLS; ++k) tot += pr[k];   // broadcast reads, deterministic
    if (c < NCLS) {
        float s = sp[c];
        int r = 0;
        for (int k = 0; k < NCLS; ++k) {
            float sk = sp[k];
            r += (sk > s || (sk == s && k < c)) ? 1 : 0;
        }
        out[(size_t)b * NCLS + c] = pr[r] / tot;
    }
}

// ---------------------------------------------------------------------------
extern "C" void kernel_launch(void* const* d_in, const int* in_sizes, int n_in,
                              void* d_out, int out_size, void* d_ws, size_t ws_size,
                              hipStream_t stream) {
    const float* x    = (const float*)d_in[0];   // [1024,768]
    const float* X    = (const float*)d_in[1];   // [50000,768]
    const float* Wp   = (const float*)d_in[2];   // [768,128]
    const float* bp   = (const float*)d_in[3];   // [128]
    const int*   Y    = (const int*)  d_in[4];   // [50000]
    const float* SPt  = (const float*)d_in[5];   // [50000,100]
    const float* SPq  = (const float*)d_in[6];   // [1024,100]
    float* out = (float*)d_out;                  // [1024,100]

    char* ws = (char*)d_ws;
    // ws layout (bytes), all 16B-aligned
    short* WpP = (short*)(ws + 0);                       //   196,608
    short* pXp = (short*)(ws + 196608);                  // 12,812,288
    short* pxq = (short*)(ws + 13008896);                //    262,144
    float* kn  = (float*)(ws + 13271040);                //    200,192
    float* qn  = (float*)(ws + 13471232);                //      4,096
    int*   lab = (int*)  (ws + 13475328);                //    200,192
    float* part= (float*)(ws + 13675520);                // NCH*1024*104*4

    // choose NCH (chunk count): 96 -> 768 blocks (3/CU), multiple of 8 so
    // XCD = linear_id % 8 = ch % 8 (b-tiles sharing pX tiles co-locate).
    const size_t base = 13675520;
    const size_t per  = (size_t)BQ * PCOLS * 4;   // bytes per chunk slice
    int NCH = 96;
    if (ws_size > base) {
        size_t fit = (ws_size - base) / per;
        if ((size_t)NCH > fit) NCH = (int)fit;
    } else {
        NCH = 8;
    }
    NCH &= ~7;                  // multiple of 8
    if (NCH < 8) NCH = 8;

    k_pack_wp<<<48, 256, 0, stream>>>(Wp, WpP);
    k_proj<<<NPAD / 128, 256, 0, stream>>>(X, WpP, bp, pXp, kn, NTRAIN);
    k_proj<<<BQ / 128,   256, 0, stream>>>(x, WpP, bp, pxq, qn, BQ);
    k_labels<<<(NPAD + 3) / 4, 256, 0, stream>>>(SPt, Y, lab);
    k_main<<<dim3(NCH, 8), 256, 0, stream>>>(pxq, pXp, qn, kn, lab, part, NCH);
    k_final<<<BQ, 128, 0, stream>>>(part, SPq, out, NCH);
}

// Round 4
// 216.047 us; speedup vs baseline: 2.1193x; 2.0877x over previous
//
#include <hip/hip_runtime.h>

// ---------------------------------------------------------------------------
// KernelClassifier: px = x@Wp+bp; pX = X@Wp+bp; Kis = exp(-||px-pX||^2/256)
// (drop self: Kis<1.0f), pred[b,lab[i]] += Kis[b,i], normalize, rank-gather.
// R2: global-atomic epilogue -> per-chunk partials + fused reduction.
// R4: fp32 LDS atomicAdd compiles to a CAS retry loop without
//     -munsafe-fp-atomics (k_main 284us, all pipes idle). Replace with
//     fixed-point u32 bins (kis * 2^21) + native ds_add_u32.
// ---------------------------------------------------------------------------

typedef short  bf8v  __attribute__((ext_vector_type(8)));   // 8 x bf16 (4 VGPR)
typedef float  f32x4 __attribute__((ext_vector_type(4)));   // MFMA C/D

#define NTRAIN 50000
#define NPAD   50048          // 391 * 128
#define NTILES 391
#define BQ     1024
#define DIN    768
#define DP     128
#define NCLS   100
#define PSTRIDE 104           // LDS pred row stride (u32); 128*104*4=53248B
#define PCOLS  104            // partial row width (>=100, float2-aligned)
#define FIXS   2097152.0f     // 2^21 fixed-point scale
#define FIXI   (1.0f / 2097152.0f)

__device__ __forceinline__ short f2bf(float x) {   // fp32 -> bf16 RNE
    unsigned u = __float_as_uint(x);
    u += 0x7FFFu + ((u >> 16) & 1u);
    return (short)(u >> 16);
}

// ---------------------------------------------------------------------------
// Kernel 0: pack Wp into B-fragment order
// ---------------------------------------------------------------------------
__global__ __launch_bounds__(256) void k_pack_wp(const float* __restrict__ Wp,
                                                 short* __restrict__ WpP) {
    int tid = blockIdx.x * 256 + threadIdx.x;
    if (tid >= 24 * 8 * 64) return;
    int l = tid & 63, cb = (tid >> 6) & 7, q = tid >> 9;
    int c = cb * 16 + (l & 15);
    int g = l >> 4;
    bf8v o;
#pragma unroll
    for (int j = 0; j < 8; ++j) {
        int k = q * 32 + g * 8 + j;
        o[j] = f2bf(Wp[k * DP + c]);
    }
    *reinterpret_cast<bf8v*>(WpP + (size_t)tid * 8) = o;
}

// ---------------------------------------------------------------------------
// Kernel 1: projection GEMM  out = rows @ Wp + bp   (K=768, Ncols=128)
// ---------------------------------------------------------------------------
__global__ __launch_bounds__(256) void k_proj(const float* __restrict__ Xin,
                                              const short* __restrict__ WpP,
                                              const float* __restrict__ bp,
                                              short* __restrict__ outP,
                                              float* __restrict__ normv,
                                              int Mreal) {
    __shared__ __align__(16) short Alds[128 * 64];   // bf16 tile, XOR-swizzled
    const int tid = threadIdx.x;
    const int w = tid >> 6, l = tid & 63, g = l >> 4, li = l & 15;
    const int rowblk = blockIdx.x * 128;

    f32x4 acc[2][8];
#pragma unroll
    for (int rb = 0; rb < 2; ++rb)
#pragma unroll
        for (int cb = 0; cb < 8; ++cb) acc[rb][cb] = (f32x4){0.f, 0.f, 0.f, 0.f};

    for (int kb = 0; kb < 12; ++kb) {          // K-step = 64
        __syncthreads();                        // protect previous reads
#pragma unroll
        for (int it = 0; it < 8; ++it) {        // stage A: 128x64 fp32 -> bf16
            int s = tid + 256 * it;             // 0..2047
            int row = s >> 4, k4 = (s & 15) * 4;
            float4 v = make_float4(0.f, 0.f, 0.f, 0.f);
            if (rowblk + row < Mreal)
                v = *reinterpret_cast<const float4*>(
                        Xin + (size_t)(rowblk + row) * DIN + kb * 64 + k4);
            unsigned lo = (unsigned short)f2bf(v.x) |
                          ((unsigned)(unsigned short)f2bf(v.y) << 16);
            unsigned hi = (unsigned short)f2bf(v.z) |
                          ((unsigned)(unsigned short)f2bf(v.w) << 16);
            int byte = (row * 128 + k4 * 2) ^ ((row & 7) << 4);
            *reinterpret_cast<uint2*>((char*)Alds + byte) = make_uint2(lo, hi);
        }
        __syncthreads();
#pragma unroll
        for (int kc = 0; kc < 2; ++kc) {
            const int q = kb * 2 + kc;
            bf8v a[2];
#pragma unroll
            for (int rb = 0; rb < 2; ++rb) {
                int row = w * 32 + rb * 16 + li;
                int byte = (row * 128 + kc * 64 + g * 16) ^ ((row & 7) << 4);
                a[rb] = *reinterpret_cast<const bf8v*>((const char*)Alds + byte);
            }
#pragma unroll
            for (int cb = 0; cb < 8; ++cb) {
                bf8v b = *reinterpret_cast<const bf8v*>(
                             WpP + (size_t)((q * 8 + cb) * 64 + l) * 8);
                acc[0][cb] = __builtin_amdgcn_mfma_f32_16x16x32_bf16(
                                 a[0], b, acc[0][cb], 0, 0, 0);
                acc[1][cb] = __builtin_amdgcn_mfma_f32_16x16x32_bf16(
                                 a[1], b, acc[1][cb], 0, 0, 0);
            }
        }
    }

    // epilogue: bias, norms, pack
    float bpv[8];
#pragma unroll
    for (int cb = 0; cb < 8; ++cb) bpv[cb] = bp[cb * 16 + li];
#pragma unroll
    for (int rb = 0; rb < 2; ++rb)
#pragma unroll
        for (int cb = 0; cb < 8; ++cb)
#pragma unroll
            for (int r = 0; r < 4; ++r) acc[rb][cb][r] += bpv[cb];

#pragma unroll
    for (int rb = 0; rb < 2; ++rb)
#pragma unroll
        for (int r = 0; r < 4; ++r) {
            float s = 0.f;
#pragma unroll
            for (int cb = 0; cb < 8; ++cb) {
                float v = acc[rb][cb][r];
                s += v * v;
            }
            s += __shfl_xor(s, 1);
            s += __shfl_xor(s, 2);
            s += __shfl_xor(s, 4);
            s += __shfl_xor(s, 8);
            int grow = rowblk + w * 32 + rb * 16 + 4 * g + r;
            if (li == 0) normv[grow] = (grow < Mreal) ? s : 1e30f;
        }

#pragma unroll
    for (int rb = 0; rb < 2; ++rb)
#pragma unroll
        for (int cb = 0; cb < 8; ++cb) {
            int d = cb * 16 + li;
            int q = d >> 5, g2 = (d & 31) >> 3, j = d & 7;
#pragma unroll
            for (int r = 0; r < 4; ++r) {
                int grow = rowblk + w * 32 + rb * 16 + 4 * g + r;
                float v = (grow < Mreal) ? acc[rb][cb][r] : 0.f;
                size_t e = ((size_t)((grow >> 4) * 4 + q) * 64 +
                            (g2 * 16 + (grow & 15))) * 8 + j;
                outP[e] = f2bf(v);
            }
        }
}

// ---------------------------------------------------------------------------
// Kernel 2: lab[i] = stable descending rank of SorP_train[i, Y[i]]
// ---------------------------------------------------------------------------
__global__ __launch_bounds__(256) void k_labels(const float* __restrict__ S,
                                                const int* __restrict__ Y,
                                                int* __restrict__ lab) {
    int w = threadIdx.x >> 6, l = threadIdx.x & 63;
    int i = blockIdx.x * 4 + w;
    if (i >= NPAD) return;
    int cnt = 0;
    if (i < NTRAIN) {
        int y = Y[i];
        float t = S[(size_t)i * NCLS + y];
        float v1 = S[(size_t)i * NCLS + l];
        bool p1 = (v1 > t) || (v1 == t && l < y);
        unsigned long long b1 = __ballot(p1);
        bool p2 = false;
        if (l < NCLS - 64) {
            float v2 = S[(size_t)i * NCLS + 64 + l];
            p2 = (v2 > t) || (v2 == t && (64 + l) < y);
        }
        unsigned long long b2 = __ballot(p2);
        cnt = __popcll(b1) + __popcll(b2);
    }
    if (l == 0) lab[i] = cnt;
}

// ---------------------------------------------------------------------------
// Kernel 4: main fused kernel. Grid (NCH, 8): ch = blockIdx.x (XCD = ch%8 so
// the 8 b-tiles sharing pX tiles co-locate per XCD), bt = blockIdx.y.
// Per i-tile: S = px @ pX^T via MFMA, Kis = exp(-(qn+kn-2dot)/256), drop-self,
// fixed-point ds_add_u32 into LDS bins by lab[i]; plain stores to partials.
// ---------------------------------------------------------------------------
__global__ __launch_bounds__(256) void k_main(const short* __restrict__ pxp,
                                              const short* __restrict__ pXp,
                                              const float* __restrict__ qn,
                                              const float* __restrict__ kn,
                                              const int* __restrict__ lab,
                                              float* __restrict__ part,
                                              int NCH) {
    __shared__ __align__(16) unsigned plds[128 * PSTRIDE];   // u32 fixed-point bins
    const int tid = threadIdx.x;
    const int w = tid >> 6, l = tid & 63, g = l >> 4, li = l & 15;
    const int ch = blockIdx.x;
    const int bt = blockIdx.y;       // 0..7

    for (int s = tid; s < 128 * PSTRIDE; s += 256) plds[s] = 0u;
    __syncthreads();                 // only barrier in the kernel

    bf8v af[2][4];                   // px A-frags, persistent
#pragma unroll
    for (int rb = 0; rb < 2; ++rb)
#pragma unroll
        for (int q = 0; q < 4; ++q) {
            int RB = bt * 8 + w * 2 + rb;
            af[rb][q] = *reinterpret_cast<const bf8v*>(
                            pxp + (size_t)((RB * 4 + q) * 64 + l) * 8);
        }
    float qnv[2][4];
#pragma unroll
    for (int rb = 0; rb < 2; ++rb)
#pragma unroll
        for (int r = 0; r < 4; ++r)
            qnv[rb][r] = qn[bt * 128 + w * 32 + rb * 16 + 4 * g + r];

#pragma unroll 1
    for (int t = ch; t < NTILES; t += NCH) {
        const int i0 = t * 128;
        for (int ib = 0; ib < 8; ++ib) {
            const int RBi = (i0 >> 4) + ib;
            bf8v bfr[4];
#pragma unroll
            for (int q = 0; q < 4; ++q)
                bfr[q] = *reinterpret_cast<const bf8v*>(
                             pXp + (size_t)((RBi * 4 + q) * 64 + l) * 8);
            f32x4 s0 = (f32x4){0.f, 0.f, 0.f, 0.f};
            f32x4 s1 = (f32x4){0.f, 0.f, 0.f, 0.f};
#pragma unroll
            for (int q = 0; q < 4; ++q) {
                s0 = __builtin_amdgcn_mfma_f32_16x16x32_bf16(af[0][q], bfr[q], s0, 0, 0, 0);
                s1 = __builtin_amdgcn_mfma_f32_16x16x32_bf16(af[1][q], bfr[q], s1, 0, 0, 0);
            }
            const int ii = i0 + ib * 16 + li;    // this lane's train index
            const float knv = kn[ii];
            const int   labv = lab[ii];
#pragma unroll
            for (int rb = 0; rb < 2; ++rb) {
                f32x4 sv = rb ? s1 : s0;
#pragma unroll
                for (int r = 0; r < 4; ++r) {
                    float sqd = qnv[rb][r] + knv - 2.f * sv[r];
                    float kis = __expf(sqd * (-1.f / 256.f));
                    kis = (kis < 1.0f) ? kis : 0.f;   // drop_self (1-1e-10 == 1.0f)
                    unsigned qv = (unsigned)__float2uint_rn(kis * FIXS);
                    int rowl = w * 32 + rb * 16 + 4 * g + r;
                    atomicAdd(&plds[rowl * PSTRIDE + labv], qv);   // ds_add_u32
                }
            }
        }
    }

    // epilogue: each wave flushes its own rows with plain vectorized stores
#pragma unroll 1
    for (int rr = 0; rr < 32; ++rr) {
        int row = w * 32 + rr;
        if (l < PCOLS / 2) {
            uint2 u = *reinterpret_cast<const uint2*>(&plds[row * PSTRIDE + l * 2]);
            float2 v = make_float2((float)u.x * FIXI, (float)u.y * FIXI);
            int grow = bt * 128 + row;
            *reinterpret_cast<float2*>(
                &part[((size_t)grow * NCH + ch) * PCOLS + l * 2]) = v;
        }
    }
}

// ---------------------------------------------------------------------------
// Kernel 5: fused reduce + normalize + rank-gather.
// Block b: pr[c] = sum_ch part[b][ch][c]; out[b,c] = pr[rank_q(b,c)] / sum.
// ---------------------------------------------------------------------------
__global__ __launch_bounds__(128) void k_final(const float* __restrict__ part,
                                               const float* __restrict__ SorPq,
                                               float* __restrict__ out,
                                               int NCH) {
    __shared__ float sp[NCLS];
    __shared__ float pr[PCOLS];
    int b = blockIdx.x, c = threadIdx.x;
    if (c < NCLS) sp[c] = SorPq[(size_t)b * NCLS + c];
    if (c < PCOLS) {
        float s = 0.f;
        const float* p = part + (size_t)b * NCH * PCOLS + c;
        for (int ch = 0; ch < NCH; ++ch) s += p[(size_t)ch * PCOLS];
        pr[c] = s;
    }
    __syncthreads();
    float tot = 0.f;
    for (int k = 0; k < NCLS; ++k) tot += pr[k];   // broadcast reads, deterministic
    if (c < NCLS) {
        float s = sp[c];
        int r = 0;
        for (int k = 0; k < NCLS; ++k) {
            float sk = sp[k];
            r += (sk > s || (sk == s && k < c)) ? 1 : 0;
        }
        out[(size_t)b * NCLS + c] = pr[r] / tot;
    }
}

// ---------------------------------------------------------------------------
extern "C" void kernel_launch(void* const* d_in, const int* in_sizes, int n_in,
                              void* d_out, int out_size, void* d_ws, size_t ws_size,
                              hipStream_t stream) {
    const float* x    = (const float*)d_in[0];   // [1024,768]
    const float* X    = (const float*)d_in[1];   // [50000,768]
    const float* Wp   = (const float*)d_in[2];   // [768,128]
    const float* bp   = (const float*)d_in[3];   // [128]
    const int*   Y    = (const int*)  d_in[4];   // [50000]
    const float* SPt  = (const float*)d_in[5];   // [50000,100]
    const float* SPq  = (const float*)d_in[6];   // [1024,100]
    float* out = (float*)d_out;                  // [1024,100]

    char* ws = (char*)d_ws;
    // ws layout (bytes), all 16B-aligned
    short* WpP = (short*)(ws + 0);                       //   196,608
    short* pXp = (short*)(ws + 196608);                  // 12,812,288
    short* pxq = (short*)(ws + 13008896);                //    262,144
    float* kn  = (float*)(ws + 13271040);                //    200,192
    float* qn  = (float*)(ws + 13471232);                //      4,096
    int*   lab = (int*)  (ws + 13475328);                //    200,192
    float* part= (float*)(ws + 13675520);                // NCH*1024*104*4

    // choose NCH (chunk count): 96 -> 768 blocks (3/CU), multiple of 8 so
    // XCD = linear_id % 8 = ch % 8 (b-tiles sharing pX tiles co-locate).
    const size_t base = 13675520;
    const size_t per  = (size_t)BQ * PCOLS * 4;   // bytes per chunk slice
    int NCH = 96;
    if (ws_size > base) {
        size_t fit = (ws_size - base) / per;
        if ((size_t)NCH > fit) NCH = (int)fit;
    } else {
        NCH = 8;
    }
    NCH &= ~7;                  // multiple of 8
    if (NCH < 8) NCH = 8;

    k_pack_wp<<<48, 256, 0, stream>>>(Wp, WpP);
    k_proj<<<NPAD / 128, 256, 0, stream>>>(X, WpP, bp, pXp, kn, NTRAIN);
    k_proj<<<BQ / 128,   256, 0, stream>>>(x, WpP, bp, pxq, qn, BQ);
    k_labels<<<(NPAD + 3) / 4, 256, 0, stream>>>(SPt, Y, lab);
    k_main<<<dim3(NCH, 8), 256, 0, stream>>>(pxq, pXp, qn, kn, lab, part, NCH);
    k_final<<<BQ, 128, 0, stream>>>(part, SPq, out, NCH);
}

// Round 5
// 168.225 us; speedup vs baseline: 2.7218x; 1.2843x over previous
//
#include <hip/hip_runtime.h>

// ---------------------------------------------------------------------------
// KernelClassifier: px = x@Wp+bp; pX = X@Wp+bp; Kis = exp(-||px-pX||^2/256)
// (drop self: Kis<1.0f), pred[b,lab[i]] += Kis[b,i], normalize, rank-gather.
// R4: fp32 LDS atomicAdd was a CAS loop -> fixed-point ds_add_u32 (451->216us).
// R5: k_proj was latency-bound (391 blocks, barrier-serialized phases, 121us,
//     HBM 9%): rewrite barrier-free, LDS-free, direct global->reg A-frags,
//     BM=64 (782 blocks, 3/CU). k_main: prefetch kn/lab per tile + double-
//     buffered B-frag loads across unrolled ib.
// ---------------------------------------------------------------------------

typedef short  bf8v  __attribute__((ext_vector_type(8)));   // 8 x bf16 (4 VGPR)
typedef float  f32x4 __attribute__((ext_vector_type(4)));   // MFMA C/D

#define NTRAIN 50000
#define NPAD   50048          // 391 * 128
#define NTILES 391
#define BQ     1024
#define DIN    768
#define DP     128
#define NCLS   100
#define PSTRIDE 104           // LDS pred row stride (u32); 128*104*4=53248B
#define PCOLS  104            // partial row width (>=100, float2-aligned)
#define FIXS   2097152.0f     // 2^21 fixed-point scale
#define FIXI   (1.0f / 2097152.0f)

__device__ __forceinline__ short f2bf(float x) {   // fp32 -> bf16 RNE
    unsigned u = __float_as_uint(x);
    u += 0x7FFFu + ((u >> 16) & 1u);
    return (short)(u >> 16);
}

// ---------------------------------------------------------------------------
// Kernel 0: pack Wp into B-fragment order: WpP[q][cb][lane][j] =
//   bf16(Wp[32q + 8*(lane>>4) + j][16cb + (lane&15)])
// ---------------------------------------------------------------------------
__global__ __launch_bounds__(256) void k_pack_wp(const float* __restrict__ Wp,
                                                 short* __restrict__ WpP) {
    int tid = blockIdx.x * 256 + threadIdx.x;
    if (tid >= 24 * 8 * 64) return;
    int l = tid & 63, cb = (tid >> 6) & 7, q = tid >> 9;
    int c = cb * 16 + (l & 15);
    int g = l >> 4;
    bf8v o;
#pragma unroll
    for (int j = 0; j < 8; ++j) {
        int k = q * 32 + g * 8 + j;
        o[j] = f2bf(Wp[k * DP + c]);
    }
    *reinterpret_cast<bf8v*>(WpP + (size_t)tid * 8) = o;
}

// ---------------------------------------------------------------------------
// Kernel 1: projection GEMM  out = rows @ Wp + bp   (K=768, Ncols=128)
// Barrier-free, LDS-free. BM=64: 4 waves, each wave 16 rows x 128 cols.
// Lane (g,li) loads A[row=li][k=q*32+g*8 .. +8) directly (32B contiguous),
// converts to bf16 in regs; B-frags stream from packed WpP (L2-hot).
// Writes fragment-packed bf16 rows + squared norms (pad rows: norm=1e30).
// ---------------------------------------------------------------------------
__global__ __launch_bounds__(256) void k_proj(const float* __restrict__ Xin,
                                              const short* __restrict__ WpP,
                                              const float* __restrict__ bp,
                                              short* __restrict__ outP,
                                              float* __restrict__ normv,
                                              int Mreal) {
    const int tid = threadIdx.x;
    const int w = tid >> 6, l = tid & 63, g = l >> 4, li = l & 15;
    const int row = blockIdx.x * 64 + w * 16 + li;   // this lane's A row
    const bool rv = (row < Mreal);
    const float* rp = Xin + (size_t)row * DIN;

    f32x4 acc[8];
#pragma unroll
    for (int cb = 0; cb < 8; ++cb) acc[cb] = (f32x4){0.f, 0.f, 0.f, 0.f};

#pragma unroll 2
    for (int q = 0; q < 24; ++q) {
        float4 a0 = make_float4(0.f, 0.f, 0.f, 0.f), a1 = a0;
        if (rv) {
            a0 = *reinterpret_cast<const float4*>(rp + q * 32 + g * 8);
            a1 = *reinterpret_cast<const float4*>(rp + q * 32 + g * 8 + 4);
        }
        bf8v af;
        af[0] = f2bf(a0.x); af[1] = f2bf(a0.y);
        af[2] = f2bf(a0.z); af[3] = f2bf(a0.w);
        af[4] = f2bf(a1.x); af[5] = f2bf(a1.y);
        af[6] = f2bf(a1.z); af[7] = f2bf(a1.w);
#pragma unroll
        for (int cb = 0; cb < 8; ++cb) {
            bf8v b = *reinterpret_cast<const bf8v*>(
                         WpP + (size_t)((q * 8 + cb) * 64 + l) * 8);
            acc[cb] = __builtin_amdgcn_mfma_f32_16x16x32_bf16(af, b, acc[cb], 0, 0, 0);
        }
    }

    // epilogue: bias, norms (reduce across the 16 lanes sharing a row), pack
    float bpv[8];
#pragma unroll
    for (int cb = 0; cb < 8; ++cb) bpv[cb] = bp[cb * 16 + li];
#pragma unroll
    for (int cb = 0; cb < 8; ++cb)
#pragma unroll
        for (int r = 0; r < 4; ++r) acc[cb][r] += bpv[cb];

#pragma unroll
    for (int r = 0; r < 4; ++r) {
        float s = 0.f;
#pragma unroll
        for (int cb = 0; cb < 8; ++cb) {
            float v = acc[cb][r];
            s += v * v;
        }
        s += __shfl_xor(s, 1);
        s += __shfl_xor(s, 2);
        s += __shfl_xor(s, 4);
        s += __shfl_xor(s, 8);
        int grow = blockIdx.x * 64 + w * 16 + 4 * g + r;
        if (li == 0) normv[grow] = (grow < Mreal) ? s : 1e30f;
    }

#pragma unroll
    for (int cb = 0; cb < 8; ++cb) {
        int d = cb * 16 + li;
        int q = d >> 5, g2 = (d & 31) >> 3, j = d & 7;
#pragma unroll
        for (int r = 0; r < 4; ++r) {
            int grow = blockIdx.x * 64 + w * 16 + 4 * g + r;
            float v = (grow < Mreal) ? acc[cb][r] : 0.f;
            size_t e = ((size_t)((grow >> 4) * 4 + q) * 64 +
                        (g2 * 16 + (grow & 15))) * 8 + j;
            outP[e] = f2bf(v);
        }
    }
}

// ---------------------------------------------------------------------------
// Kernel 2: lab[i] = stable descending rank of SorP_train[i, Y[i]]
// ---------------------------------------------------------------------------
__global__ __launch_bounds__(256) void k_labels(const float* __restrict__ S,
                                                const int* __restrict__ Y,
                                                int* __restrict__ lab) {
    int w = threadIdx.x >> 6, l = threadIdx.x & 63;
    int i = blockIdx.x * 4 + w;
    if (i >= NPAD) return;
    int cnt = 0;
    if (i < NTRAIN) {
        int y = Y[i];
        float t = S[(size_t)i * NCLS + y];
        float v1 = S[(size_t)i * NCLS + l];
        bool p1 = (v1 > t) || (v1 == t && l < y);
        unsigned long long b1 = __ballot(p1);
        bool p2 = false;
        if (l < NCLS - 64) {
            float v2 = S[(size_t)i * NCLS + 64 + l];
            p2 = (v2 > t) || (v2 == t && (64 + l) < y);
        }
        unsigned long long b2 = __ballot(p2);
        cnt = __popcll(b1) + __popcll(b2);
    }
    if (l == 0) lab[i] = cnt;
}

// ---------------------------------------------------------------------------
// Kernel 4: main fused kernel. Grid (NCH, 8): ch = blockIdx.x (XCD = ch%8),
// bt = blockIdx.y. Per i-tile: S = px @ pX^T via MFMA (B-frags double-buffered
// across unrolled ib; kn/lab prefetched per tile), Kis = exp(-(qn+kn-2dot)/256),
// drop-self, fixed-point ds_add_u32 bins by lab[i]; plain stores to partials.
// ---------------------------------------------------------------------------
__global__ __launch_bounds__(256) void k_main(const short* __restrict__ pxp,
                                              const short* __restrict__ pXp,
                                              const float* __restrict__ qn,
                                              const float* __restrict__ kn,
                                              const int* __restrict__ lab,
                                              float* __restrict__ part,
                                              int NCH) {
    __shared__ __align__(16) unsigned plds[128 * PSTRIDE];   // u32 fixed-point bins
    const int tid = threadIdx.x;
    const int w = tid >> 6, l = tid & 63, g = l >> 4, li = l & 15;
    const int ch = blockIdx.x;
    const int bt = blockIdx.y;       // 0..7

    for (int s = tid; s < 128 * PSTRIDE; s += 256) plds[s] = 0u;
    __syncthreads();                 // only barrier in the kernel

    bf8v af[2][4];                   // px A-frags, persistent
#pragma unroll
    for (int rb = 0; rb < 2; ++rb)
#pragma unroll
        for (int q = 0; q < 4; ++q) {
            int RB = bt * 8 + w * 2 + rb;
            af[rb][q] = *reinterpret_cast<const bf8v*>(
                            pxp + (size_t)((RB * 4 + q) * 64 + l) * 8);
        }
    float qnv[2][4];
#pragma unroll
    for (int rb = 0; rb < 2; ++rb)
#pragma unroll
        for (int r = 0; r < 4; ++r)
            qnv[rb][r] = qn[bt * 128 + w * 32 + rb * 16 + 4 * g + r];

#pragma unroll 1
    for (int t = ch; t < NTILES; t += NCH) {
        const int i0 = t * 128;
        // prefetch the whole tile's kn/lab (per-lane: 8 values each)
        float knv8[8];
        int   labv8[8];
#pragma unroll
        for (int ib = 0; ib < 8; ++ib) {
            knv8[ib]  = kn[i0 + ib * 16 + li];
            labv8[ib] = lab[i0 + ib * 16 + li];
        }
        // double-buffered B-frag pipeline across fully-unrolled ib
        bf8v bfr2[2][4];
        {
            const int RBi = (i0 >> 4);
#pragma unroll
            for (int q = 0; q < 4; ++q)
                bfr2[0][q] = *reinterpret_cast<const bf8v*>(
                                 pXp + (size_t)((RBi * 4 + q) * 64 + l) * 8);
        }
#pragma unroll
        for (int ib = 0; ib < 8; ++ib) {
            if (ib < 7) {                         // prefetch next sub-tile
                const int RBn = (i0 >> 4) + ib + 1;
#pragma unroll
                for (int q = 0; q < 4; ++q)
                    bfr2[(ib + 1) & 1][q] = *reinterpret_cast<const bf8v*>(
                        pXp + (size_t)((RBn * 4 + q) * 64 + l) * 8);
            }
            f32x4 s0 = (f32x4){0.f, 0.f, 0.f, 0.f};
            f32x4 s1 = (f32x4){0.f, 0.f, 0.f, 0.f};
#pragma unroll
            for (int q = 0; q < 4; ++q) {
                s0 = __builtin_amdgcn_mfma_f32_16x16x32_bf16(af[0][q], bfr2[ib & 1][q], s0, 0, 0, 0);
                s1 = __builtin_amdgcn_mfma_f32_16x16x32_bf16(af[1][q], bfr2[ib & 1][q], s1, 0, 0, 0);
            }
            const float knv  = knv8[ib];
            const int   labv = labv8[ib];
#pragma unroll
            for (int rb = 0; rb < 2; ++rb) {
                f32x4 sv = rb ? s1 : s0;
#pragma unroll
                for (int r = 0; r < 4; ++r) {
                    float sqd = qnv[rb][r] + knv - 2.f * sv[r];
                    float kis = __expf(sqd * (-1.f / 256.f));
                    kis = (kis < 1.0f) ? kis : 0.f;   // drop_self (1-1e-10 == 1.0f)
                    unsigned qv = (unsigned)__float2uint_rn(kis * FIXS);
                    int rowl = w * 32 + rb * 16 + 4 * g + r;
                    atomicAdd(&plds[rowl * PSTRIDE + labv], qv);   // ds_add_u32
                }
            }
        }
    }

    // epilogue: each wave flushes its own rows with plain vectorized stores
#pragma unroll 1
    for (int rr = 0; rr < 32; ++rr) {
        int row = w * 32 + rr;
        if (l < PCOLS / 2) {
            uint2 u = *reinterpret_cast<const uint2*>(&plds[row * PSTRIDE + l * 2]);
            float2 v = make_float2((float)u.x * FIXI, (float)u.y * FIXI);
            int grow = bt * 128 + row;
            *reinterpret_cast<float2*>(
                &part[((size_t)grow * NCH + ch) * PCOLS + l * 2]) = v;
        }
    }
}

// ---------------------------------------------------------------------------
// Kernel 5: fused reduce + normalize + rank-gather.
// Block b: pr[c] = sum_ch part[b][ch][c]; out[b,c] = pr[rank_q(b,c)] / sum.
// ---------------------------------------------------------------------------
__global__ __launch_bounds__(128) void k_final(const float* __restrict__ part,
                                               const float* __restrict__ SorPq,
                                               float* __restrict__ out,
                                               int NCH) {
    __shared__ float sp[NCLS];
    __shared__ float pr[PCOLS];
    int b = blockIdx.x, c = threadIdx.x;
    if (c < NCLS) sp[c] = SorPq[(size_t)b * NCLS + c];
    if (c < PCOLS) {
        float s = 0.f;
        const float* p = part + (size_t)b * NCH * PCOLS + c;
        for (int ch = 0; ch < NCH; ++ch) s += p[(size_t)ch * PCOLS];
        pr[c] = s;
    }
    __syncthreads();
    float tot = 0.f;
    for (int k = 0; k < NCLS; ++k) tot += pr[k];   // broadcast reads, deterministic
    if (c < NCLS) {
        float s = sp[c];
        int r = 0;
        for (int k = 0; k < NCLS; ++k) {
            float sk = sp[k];
            r += (sk > s || (sk == s && k < c)) ? 1 : 0;
        }
        out[(size_t)b * NCLS + c] = pr[r] / tot;
    }
}

// ---------------------------------------------------------------------------
extern "C" void kernel_launch(void* const* d_in, const int* in_sizes, int n_in,
                              void* d_out, int out_size, void* d_ws, size_t ws_size,
                              hipStream_t stream) {
    const float* x    = (const float*)d_in[0];   // [1024,768]
    const float* X    = (const float*)d_in[1];   // [50000,768]
    const float* Wp   = (const float*)d_in[2];   // [768,128]
    const float* bp   = (const float*)d_in[3];   // [128]
    const int*   Y    = (const int*)  d_in[4];   // [50000]
    const float* SPt  = (const float*)d_in[5];   // [50000,100]
    const float* SPq  = (const float*)d_in[6];   // [1024,100]
    float* out = (float*)d_out;                  // [1024,100]

    char* ws = (char*)d_ws;
    // ws layout (bytes), all 16B-aligned
    short* WpP = (short*)(ws + 0);                       //   196,608
    short* pXp = (short*)(ws + 196608);                  // 12,812,288
    short* pxq = (short*)(ws + 13008896);                //    262,144
    float* kn  = (float*)(ws + 13271040);                //    200,192
    float* qn  = (float*)(ws + 13471232);                //      4,096
    int*   lab = (int*)  (ws + 13475328);                //    200,192
    float* part= (float*)(ws + 13675520);                // NCH*1024*104*4

    // choose NCH (chunk count): 96 -> 768 blocks (3/CU), multiple of 8 so
    // XCD = linear_id % 8 = ch % 8 (b-tiles sharing pX tiles co-locate).
    const size_t base = 13675520;
    const size_t per  = (size_t)BQ * PCOLS * 4;   // bytes per chunk slice
    int NCH = 96;
    if (ws_size > base) {
        size_t fit = (ws_size - base) / per;
        if ((size_t)NCH > fit) NCH = (int)fit;
    } else {
        NCH = 8;
    }
    NCH &= ~7;                  // multiple of 8
    if (NCH < 8) NCH = 8;

    k_pack_wp<<<48, 256, 0, stream>>>(Wp, WpP);
    k_proj<<<NPAD / 64, 256, 0, stream>>>(X, WpP, bp, pXp, kn, NTRAIN);
    k_proj<<<BQ / 64,   256, 0, stream>>>(x, WpP, bp, pxq, qn, BQ);
    k_labels<<<(NPAD + 3) / 4, 256, 0, stream>>>(SPt, Y, lab);
    k_main<<<dim3(NCH, 8), 256, 0, stream>>>(pxq, pXp, qn, kn, lab, part, NCH);
    k_final<<<BQ, 128, 0, stream>>>(part, SPq, out, NCH);
}

// Round 7
// 150.928 us; speedup vs baseline: 3.0338x; 1.1146x over previous
//
#include <hip/hip_runtime.h>

// ---------------------------------------------------------------------------
// KernelClassifier: px = x@Wp+bp; pX = X@Wp+bp; Kis = exp(-||px-pX||^2/256)
// (drop self: Kis<1.0f), pred[b,lab[i]] += Kis[b,i], normalize, rank-gather.
// R4: fp32 LDS atomicAdd was a CAS loop -> fixed-point ds_add_u32 (451->216us).
// R5: barrier-free k_proj (121->89us); VGPR=44 => compiler didn't pipeline.
// R6: explicit SW pipeline — FAILED: prefetch wrote the ring slot BEFORE the
//     consume read ((2*(q+4))&7 == (2*q)&7), shipping chunk q+4 to step q.
// R7: consume-then-refill ring ordering (copy a0/a1 out first). No other
//     change vs R6 for a clean A/B on the pipelining theory.
// ---------------------------------------------------------------------------

typedef short  bf8v  __attribute__((ext_vector_type(8)));   // 8 x bf16 (4 VGPR)
typedef float  f32x4 __attribute__((ext_vector_type(4)));   // MFMA C/D

#define NTRAIN 50000
#define NPAD   50048          // 391 * 128
#define NTILES 391
#define BQ     1024
#define DIN    768
#define DP     128
#define NCLS   100
#define PSTRIDE 104           // LDS pred row stride (u32); 128*104*4=53248B
#define PCOLS  104            // partial row width (>=100, float2-aligned)
#define FIXS   2097152.0f     // 2^21 fixed-point scale
#define FIXI   (1.0f / 2097152.0f)

__device__ __forceinline__ short f2bf(float x) {   // fp32 -> bf16 RNE
    unsigned u = __float_as_uint(x);
    u += 0x7FFFu + ((u >> 16) & 1u);
    return (short)(u >> 16);
}

// ---------------------------------------------------------------------------
// Kernel 0: pack Wp into B-fragment order: WpP[q][cb][lane][j] =
//   bf16(Wp[32q + 8*(lane>>4) + j][16cb + (lane&15)])
// ---------------------------------------------------------------------------
__global__ __launch_bounds__(256) void k_pack_wp(const float* __restrict__ Wp,
                                                 short* __restrict__ WpP) {
    int tid = blockIdx.x * 256 + threadIdx.x;
    if (tid >= 24 * 8 * 64) return;
    int l = tid & 63, cb = (tid >> 6) & 7, q = tid >> 9;
    int c = cb * 16 + (l & 15);
    int g = l >> 4;
    bf8v o;
#pragma unroll
    for (int j = 0; j < 8; ++j) {
        int k = q * 32 + g * 8 + j;
        o[j] = f2bf(Wp[k * DP + c]);
    }
    *reinterpret_cast<bf8v*>(WpP + (size_t)tid * 8) = o;
}

// ---------------------------------------------------------------------------
// Kernel 1: projection GEMM  out = rows @ Wp + bp   (K=768, Ncols=128)
// Barrier-free, LDS-free, explicitly software-pipelined.
// BM=64: 4 waves, each wave 16 rows x 128 cols. Lane (g,li): A row = li,
// k-chunk = q*32 + g*8. X ring depth 4 (consume-then-refill!); WpP dbuf.
// Rows clamped (not predicated); pad rows zeroed in epilogue.
// ---------------------------------------------------------------------------
__global__ __launch_bounds__(256) void k_proj(const float* __restrict__ Xin,
                                              const short* __restrict__ WpP,
                                              const float* __restrict__ bp,
                                              short* __restrict__ outP,
                                              float* __restrict__ normv,
                                              int Mreal) {
    const int tid = threadIdx.x;
    const int w = tid >> 6, l = tid & 63, g = l >> 4, li = l & 15;
    const int row0 = blockIdx.x * 64 + w * 16 + li;      // this lane's A row
    const int row  = (row0 < Mreal) ? row0 : (Mreal - 1); // clamp; zero later
    const float* rp = Xin + (size_t)row * DIN + g * 8;
    const short* wq = WpP + (size_t)l * 8;

    f32x4 acc[8];
#pragma unroll
    for (int cb = 0; cb < 8; ++cb) acc[cb] = (f32x4){0.f, 0.f, 0.f, 0.f};

    // X prefetch ring: 4 q-steps in flight (8 x float4)
    float4 xa[8];
#pragma unroll
    for (int p = 0; p < 4; ++p) {
        xa[2 * p]     = *reinterpret_cast<const float4*>(rp + p * 32);
        xa[2 * p + 1] = *reinterpret_cast<const float4*>(rp + p * 32 + 4);
    }
    // WpP double buffer: 1 q-step ahead (8 x bf8v per buffer)
    bf8v bq[2][8];
#pragma unroll
    for (int cb = 0; cb < 8; ++cb)
        bq[0][cb] = *reinterpret_cast<const bf8v*>(wq + (size_t)cb * 512);

#pragma unroll
    for (int q = 0; q < 24; ++q) {
        // consume current step's X FIRST (copy out of the ring slot)...
        float4 a0 = xa[(2 * q) & 7], a1 = xa[(2 * q + 1) & 7];
        // ...then refill the freed slots with step q+4
        if (q + 4 < 24) {
            xa[(2 * q) & 7]     = *reinterpret_cast<const float4*>(rp + (q + 4) * 32);
            xa[(2 * q + 1) & 7] = *reinterpret_cast<const float4*>(rp + (q + 4) * 32 + 4);
        }
        // prefetch next WpP step (L2-hot; writes the other buffer)
        if (q + 1 < 24) {
#pragma unroll
            for (int cb = 0; cb < 8; ++cb)
                bq[(q + 1) & 1][cb] = *reinterpret_cast<const bf8v*>(
                    wq + (size_t)((q + 1) * 8 + cb) * 512);
        }
        bf8v af;
        af[0] = f2bf(a0.x); af[1] = f2bf(a0.y);
        af[2] = f2bf(a0.z); af[3] = f2bf(a0.w);
        af[4] = f2bf(a1.x); af[5] = f2bf(a1.y);
        af[6] = f2bf(a1.z); af[7] = f2bf(a1.w);
#pragma unroll
        for (int cb = 0; cb < 8; ++cb)
            acc[cb] = __builtin_amdgcn_mfma_f32_16x16x32_bf16(af, bq[q & 1][cb], acc[cb], 0, 0, 0);
    }

    // epilogue: bias, norms (reduce across 16 lanes sharing a C-row), pack
    float bpv[8];
#pragma unroll
    for (int cb = 0; cb < 8; ++cb) bpv[cb] = bp[cb * 16 + li];
#pragma unroll
    for (int cb = 0; cb < 8; ++cb)
#pragma unroll
        for (int r = 0; r < 4; ++r) acc[cb][r] += bpv[cb];

#pragma unroll
    for (int r = 0; r < 4; ++r) {
        float s = 0.f;
#pragma unroll
        for (int cb = 0; cb < 8; ++cb) {
            float v = acc[cb][r];
            s += v * v;
        }
        s += __shfl_xor(s, 1);
        s += __shfl_xor(s, 2);
        s += __shfl_xor(s, 4);
        s += __shfl_xor(s, 8);
        int grow = blockIdx.x * 64 + w * 16 + 4 * g + r;
        if (li == 0) normv[grow] = (grow < Mreal) ? s : 1e30f;
    }

#pragma unroll
    for (int cb = 0; cb < 8; ++cb) {
        int d = cb * 16 + li;
        int q = d >> 5, g2 = (d & 31) >> 3, j = d & 7;
#pragma unroll
        for (int r = 0; r < 4; ++r) {
            int grow = blockIdx.x * 64 + w * 16 + 4 * g + r;
            float v = (grow < Mreal) ? acc[cb][r] : 0.f;
            size_t e = ((size_t)((grow >> 4) * 4 + q) * 64 +
                        (g2 * 16 + (grow & 15))) * 8 + j;
            outP[e] = f2bf(v);
        }
    }
}

// ---------------------------------------------------------------------------
// Kernel 2: lab[i] = stable descending rank of SorP_train[i, Y[i]]
// ---------------------------------------------------------------------------
__global__ __launch_bounds__(256) void k_labels(const float* __restrict__ S,
                                                const int* __restrict__ Y,
                                                int* __restrict__ lab) {
    int w = threadIdx.x >> 6, l = threadIdx.x & 63;
    int i = blockIdx.x * 4 + w;
    if (i >= NPAD) return;
    int cnt = 0;
    if (i < NTRAIN) {
        int y = Y[i];
        float t = S[(size_t)i * NCLS + y];
        float v1 = S[(size_t)i * NCLS + l];
        bool p1 = (v1 > t) || (v1 == t && l < y);
        unsigned long long b1 = __ballot(p1);
        bool p2 = false;
        if (l < NCLS - 64) {
            float v2 = S[(size_t)i * NCLS + 64 + l];
            p2 = (v2 > t) || (v2 == t && (64 + l) < y);
        }
        unsigned long long b2 = __ballot(p2);
        cnt = __popcll(b1) + __popcll(b2);
    }
    if (l == 0) lab[i] = cnt;
}

// ---------------------------------------------------------------------------
// Kernel 4: main fused kernel. Grid (NCH, 8): ch = blockIdx.x (XCD = ch%8),
// bt = blockIdx.y. Per i-tile: S = px @ pX^T via MFMA (B-frags double-buffered
// across unrolled ib; kn/lab prefetched per tile), Kis = exp(-(qn+kn-2dot)/256),
// drop-self, fixed-point ds_add_u32 bins by lab[i]; plain stores to partials.
// ---------------------------------------------------------------------------
__global__ __launch_bounds__(256) void k_main(const short* __restrict__ pxp,
                                              const short* __restrict__ pXp,
                                              const float* __restrict__ qn,
                                              const float* __restrict__ kn,
                                              const int* __restrict__ lab,
                                              float* __restrict__ part,
                                              int NCH) {
    __shared__ __align__(16) unsigned plds[128 * PSTRIDE];   // u32 fixed-point bins
    const int tid = threadIdx.x;
    const int w = tid >> 6, l = tid & 63, g = l >> 4, li = l & 15;
    const int ch = blockIdx.x;
    const int bt = blockIdx.y;       // 0..7

    for (int s = tid; s < 128 * PSTRIDE; s += 256) plds[s] = 0u;
    __syncthreads();                 // only barrier in the kernel

    bf8v af[2][4];                   // px A-frags, persistent
#pragma unroll
    for (int rb = 0; rb < 2; ++rb)
#pragma unroll
        for (int q = 0; q < 4; ++q) {
            int RB = bt * 8 + w * 2 + rb;
            af[rb][q] = *reinterpret_cast<const bf8v*>(
                            pxp + (size_t)((RB * 4 + q) * 64 + l) * 8);
        }
    float qnv[2][4];
#pragma unroll
    for (int rb = 0; rb < 2; ++rb)
#pragma unroll
        for (int r = 0; r < 4; ++r)
            qnv[rb][r] = qn[bt * 128 + w * 32 + rb * 16 + 4 * g + r];

#pragma unroll 1
    for (int t = ch; t < NTILES; t += NCH) {
        const int i0 = t * 128;
        // prefetch the whole tile's kn/lab (per-lane: 8 values each)
        float knv8[8];
        int   labv8[8];
#pragma unroll
        for (int ib = 0; ib < 8; ++ib) {
            knv8[ib]  = kn[i0 + ib * 16 + li];
            labv8[ib] = lab[i0 + ib * 16 + li];
        }
        // double-buffered B-frag pipeline across fully-unrolled ib
        bf8v bfr2[2][4];
        {
            const int RBi = (i0 >> 4);
#pragma unroll
            for (int q = 0; q < 4; ++q)
                bfr2[0][q] = *reinterpret_cast<const bf8v*>(
                                 pXp + (size_t)((RBi * 4 + q) * 64 + l) * 8);
        }
#pragma unroll
        for (int ib = 0; ib < 8; ++ib) {
            if (ib < 7) {                         // prefetch next sub-tile
                const int RBn = (i0 >> 4) + ib + 1;
#pragma unroll
                for (int q = 0; q < 4; ++q)
                    bfr2[(ib + 1) & 1][q] = *reinterpret_cast<const bf8v*>(
                        pXp + (size_t)((RBn * 4 + q) * 64 + l) * 8);
            }
            f32x4 s0 = (f32x4){0.f, 0.f, 0.f, 0.f};
            f32x4 s1 = (f32x4){0.f, 0.f, 0.f, 0.f};
#pragma unroll
            for (int q = 0; q < 4; ++q) {
                s0 = __builtin_amdgcn_mfma_f32_16x16x32_bf16(af[0][q], bfr2[ib & 1][q], s0, 0, 0, 0);
                s1 = __builtin_amdgcn_mfma_f32_16x16x32_bf16(af[1][q], bfr2[ib & 1][q], s1, 0, 0, 0);
            }
            const float knv  = knv8[ib];
            const int   labv = labv8[ib];
#pragma unroll
            for (int rb = 0; rb < 2; ++rb) {
                f32x4 sv = rb ? s1 : s0;
#pragma unroll
                for (int r = 0; r < 4; ++r) {
                    float sqd = qnv[rb][r] + knv - 2.f * sv[r];
                    float kis = __expf(sqd * (-1.f / 256.f));
                    kis = (kis < 1.0f) ? kis : 0.f;   // drop_self (1-1e-10 == 1.0f)
                    unsigned qv = (unsigned)__float2uint_rn(kis * FIXS);
                    int rowl = w * 32 + rb * 16 + 4 * g + r;
                    atomicAdd(&plds[rowl * PSTRIDE + labv], qv);   // ds_add_u32
                }
            }
        }
    }

    // epilogue: each wave flushes its own rows with plain vectorized stores
#pragma unroll 1
    for (int rr = 0; rr < 32; ++rr) {
        int row = w * 32 + rr;
        if (l < PCOLS / 2) {
            uint2 u = *reinterpret_cast<const uint2*>(&plds[row * PSTRIDE + l * 2]);
            float2 v = make_float2((float)u.x * FIXI, (float)u.y * FIXI);
            int grow = bt * 128 + row;
            *reinterpret_cast<float2*>(
                &part[((size_t)grow * NCH + ch) * PCOLS + l * 2]) = v;
        }
    }
}

// ---------------------------------------------------------------------------
// Kernel 5: fused reduce + normalize + rank-gather.
// Block b: pr[c] = sum_ch part[b][ch][c]; out[b,c] = pr[rank_q(b,c)] / sum.
// ---------------------------------------------------------------------------
__global__ __launch_bounds__(128) void k_final(const float* __restrict__ part,
                                               const float* __restrict__ SorPq,
                                               float* __restrict__ out,
                                               int NCH) {
    __shared__ float sp[NCLS];
    __shared__ float pr[PCOLS];
    int b = blockIdx.x, c = threadIdx.x;
    if (c < NCLS) sp[c] = SorPq[(size_t)b * NCLS + c];
    if (c < PCOLS) {
        float s = 0.f;
        const float* p = part + (size_t)b * NCH * PCOLS + c;
        for (int ch = 0; ch < NCH; ++ch) s += p[(size_t)ch * PCOLS];
        pr[c] = s;
    }
    __syncthreads();
    float tot = 0.f;
    for (int k = 0; k < NCLS; ++k) tot += pr[k];   // broadcast reads, deterministic
    if (c < NCLS) {
        float s = sp[c];
        int r = 0;
        for (int k = 0; k < NCLS; ++k) {
            float sk = sp[k];
            r += (sk > s || (sk == s && k < c)) ? 1 : 0;
        }
        out[(size_t)b * NCLS + c] = pr[r] / tot;
    }
}

// ---------------------------------------------------------------------------
extern "C" void kernel_launch(void* const* d_in, const int* in_sizes, int n_in,
                              void* d_out, int out_size, void* d_ws, size_t ws_size,
                              hipStream_t stream) {
    const float* x    = (const float*)d_in[0];   // [1024,768]
    const float* X    = (const float*)d_in[1];   // [50000,768]
    const float* Wp   = (const float*)d_in[2];   // [768,128]
    const float* bp   = (const float*)d_in[3];   // [128]
    const int*   Y    = (const int*)  d_in[4];   // [50000]
    const float* SPt  = (const float*)d_in[5];   // [50000,100]
    const float* SPq  = (const float*)d_in[6];   // [1024,100]
    float* out = (float*)d_out;                  // [1024,100]

    char* ws = (char*)d_ws;
    // ws layout (bytes), all 16B-aligned
    short* WpP = (short*)(ws + 0);                       //   196,608
    short* pXp = (short*)(ws + 196608);                  // 12,812,288
    short* pxq = (short*)(ws + 13008896);                //    262,144
    float* kn  = (float*)(ws + 13271040);                //    200,192
    float* qn  = (float*)(ws + 13471232);                //      4,096
    int*   lab = (int*)  (ws + 13475328);                //    200,192
    float* part= (float*)(ws + 13675520);                // NCH*1024*104*4

    // choose NCH (chunk count): 96 -> 768 blocks (3/CU), multiple of 8 so
    // XCD = linear_id % 8 = ch % 8 (b-tiles sharing pX tiles co-locate).
    const size_t base = 13675520;
    const size_t per  = (size_t)BQ * PCOLS * 4;   // bytes per chunk slice
    int NCH = 96;
    if (ws_size > base) {
        size_t fit = (ws_size - base) / per;
        if ((size_t)NCH > fit) NCH = (int)fit;
    } else {
        NCH = 8;
    }
    NCH &= ~7;                  // multiple of 8
    if (NCH < 8) NCH = 8;

    k_pack_wp<<<48, 256, 0, stream>>>(Wp, WpP);
    k_proj<<<NPAD / 64, 256, 0, stream>>>(X, WpP, bp, pXp, kn, NTRAIN);
    k_proj<<<(BQ + 63) / 64, 256, 0, stream>>>(x, WpP, bp, pxq, qn, BQ);
    k_labels<<<(NPAD + 3) / 4, 256, 0, stream>>>(SPt, Y, lab);
    k_main<<<dim3(NCH, 8), 256, 0, stream>>>(pxq, pXp, qn, kn, lab, part, NCH);
    k_final<<<BQ, 128, 0, stream>>>(part, SPq, out, NCH);
}